// Round 1
// baseline (12181.020 us; speedup 1.0000x reference)
//
#include <hip/hip_runtime.h>

// SentimentAnalyzer: 2-layer (fake-)bidirectional GRU, S=400 B=128 H=512.
// Phases: pack weights -> gather emb -> GEMM gi0 -> persistent recurrence L0
//         -> GEMM gi1 -> persistent recurrence L1 -> classifier.
// f16 MFMA everywhere (f32 accum + f32 gate math + f32 master h).

typedef unsigned int u32;
typedef unsigned short u16;
typedef __attribute__((ext_vector_type(8))) _Float16 f16x8;
typedef __attribute__((ext_vector_type(4))) float f32x4;
typedef __attribute__((ext_vector_type(4))) u32 u32x4;

#define AS1 __attribute__((address_space(1)))
#define AS3 __attribute__((address_space(3)))

__device__ __forceinline__ void gl_lds16(const void* g, void* l) {
  __builtin_amdgcn_global_load_lds((AS1 void*)g, (AS3 void*)l, 16, 0, 0);
}
__device__ __forceinline__ u16 f2h(float f) {
  _Float16 h = (_Float16)f;
  return __builtin_bit_cast(u16, h);
}
__device__ __forceinline__ float h2f(u16 u) {
  return (float)__builtin_bit_cast(_Float16, u);
}
__device__ __forceinline__ u32 pack2(float a, float b) {
  return (u32)f2h(a) | ((u32)f2h(b) << 16);
}
__device__ __forceinline__ float sigm(float x) {
  x = fminf(fmaxf(x, -30.f), 30.f);
  return 1.f / (1.f + __expf(-x));
}
__device__ __forceinline__ float tanh_(float x) {
  x = fminf(fmaxf(x, -15.f), 15.f);
  float e = __expf(2.f * x);
  return (e - 1.f) / (e + 1.f);
}

// Device-wide barrier for a small co-resident grid. bar[0]=count, bar[1]=gen.
__device__ __forceinline__ void gridbar(unsigned* bar, unsigned nblk) {
  __syncthreads();
  if (threadIdx.x == 0) {
    __builtin_amdgcn_fence(__ATOMIC_RELEASE, "agent");
    unsigned g = __hip_atomic_load(&bar[1], __ATOMIC_RELAXED, __HIP_MEMORY_SCOPE_AGENT);
    unsigned a = __hip_atomic_fetch_add(&bar[0], 1u, __ATOMIC_RELAXED, __HIP_MEMORY_SCOPE_AGENT);
    if (a == nblk - 1u) {
      __hip_atomic_store(&bar[0], 0u, __ATOMIC_RELAXED, __HIP_MEMORY_SCOPE_AGENT);
      __hip_atomic_fetch_add(&bar[1], 1u, __ATOMIC_RELAXED, __HIP_MEMORY_SCOPE_AGENT);
    } else {
      while (__hip_atomic_load(&bar[1], __ATOMIC_RELAXED, __HIP_MEMORY_SCOPE_AGENT) == g)
        __builtin_amdgcn_s_sleep(1);
    }
    __builtin_amdgcn_fence(__ATOMIC_ACQUIRE, "agent");
  }
  __syncthreads();
}

// ---------------- pack kernels ----------------
// B matrices stored N-major (= Wih layout directly), f16, K zero-padded.
__global__ __launch_bounds__(256) void pack_wih(const float* __restrict__ W,
                                                u16* __restrict__ out, int K, int Kp, int total) {
  int idx = blockIdx.x * 256 + threadIdx.x;
  if (idx >= total) return;
  int n = idx / Kp, k = idx - n * Kp;
  out[idx] = (k < K) ? f2h(W[(size_t)n * K + k]) : (u16)0;
}

// Whh packed into MFMA B-fragment order:
// [d][c(16)][qt(6)][kt(16)][lane(64)][e(8)], value = Whh[d][g*512 + c*32 + jj][k]
// with q = qt*16 + (lane&15), g=q>>5, jj=q&31, k = kt*32 + ((lane>>4)&3)*8 + e.
__global__ __launch_bounds__(256) void pack_whh(const float* __restrict__ W,
                                                u16* __restrict__ out) {
  int idx = blockIdx.x * 256 + threadIdx.x;  // 196608 total
  int l = idx & 63;
  int kt = (idx >> 6) & 15;
  int t2 = idx >> 10;
  int qt = t2 % 6;
  int t3 = t2 / 6;
  int cc = t3 & 15, d = t3 >> 4;
  int q = qt * 16 + (l & 15);
  int g = q >> 5, jj = q & 31;
  int row = g * 512 + cc * 32 + jj;
  int kb = kt * 32 + ((l >> 4) & 3) * 8;
  const float* src = W + ((size_t)d * 1536 + row) * 512 + kb;
  u32* o = (u32*)(out + (size_t)idx * 8);
#pragma unroll
  for (int e2 = 0; e2 < 4; ++e2) o[e2] = pack2(src[2 * e2], src[2 * e2 + 1]);
}

// biasP[d][slot][512]: slot0 = bih_r+bhh_r, 1 = bih_z+bhh_z, 2 = bih_n, 3 = bhh_n
__global__ __launch_bounds__(256) void pack_bias(const float* __restrict__ bih,
                                                 const float* __restrict__ bhh,
                                                 float* __restrict__ out) {
  int idx = blockIdx.x * 256 + threadIdx.x;  // 4096
  int j = idx & 511;
  int slot = (idx >> 9) & 3;
  int d = idx >> 11;
  float v;
  if (slot == 0) v = bih[d * 1536 + j] + bhh[d * 1536 + j];
  else if (slot == 1) v = bih[d * 1536 + 512 + j] + bhh[d * 1536 + 512 + j];
  else if (slot == 2) v = bih[d * 1536 + 1024 + j];
  else v = bhh[d * 1536 + 1024 + j];
  out[idx] = v;
}

// embedded gather + f16 cast, K padded 300->320. out u32 = 2 f16.
__global__ __launch_bounds__(256) void gather_emb(const int* __restrict__ X,
                                                  const float* __restrict__ emb,
                                                  u32* __restrict__ out, int t0, int total) {
  int idx = blockIdx.x * 256 + threadIdx.x;
  if (idx >= total) return;
  int r = idx / 160, kp = idx - r * 160;
  int k = kp * 2;
  int tok = X[t0 * 128 + r];
  float v0 = (k < 300) ? emb[(size_t)tok * 300 + k] : 0.f;
  float v1 = (k < 299) ? emb[(size_t)tok * 300 + k + 1] : 0.f;
  out[idx] = pack2(v0, v1);
}

// ---------------- big GEMM: C[M][N] = A[M][K] * B[N][K]^T, f16 in/out ----------------
// 128x128 tile, 4 waves (2x2 of 64x64), global_load_lds staging (m97 structure).
__global__ __launch_bounds__(256) void gemm_f16(const u16* __restrict__ A,
                                                const u16* __restrict__ B,
                                                u16* __restrict__ C, int N, int K) {
  __shared__ u16 As[4096];
  __shared__ u16 Bs[4096];
  const int tid = threadIdx.x;
  const int w = tid >> 6, l = tid & 63;
  const long m0 = (long)blockIdx.y << 7;
  const long n0 = (long)blockIdx.x << 7;
  const int wm = w >> 1, wn = w & 1;
  f32x4 acc[4][4] = {};

  const int srow = w * 16 + (l >> 2);
  const int scol = (l & 3) * 8;
  const u16* ga = A + (m0 + srow) * K + scol;
  const u16* gb = B + (n0 + srow) * K + scol;
  u16* lA = &As[w * 512];
  u16* lB = &Bs[w * 512];

  for (int k0 = 0; k0 < K; k0 += 32) {
    gl_lds16(ga + k0, lA);
    gl_lds16(ga + 64 * K + k0, lA + 2048);
    gl_lds16(gb + k0, lB);
    gl_lds16(gb + 64 * K + k0, lB + 2048);
    __syncthreads();
    f16x8 af[4], bf[4];
#pragma unroll
    for (int mi = 0; mi < 4; ++mi)
      af[mi] = *(const f16x8*)&As[(wm * 64 + mi * 16 + (l & 15)) * 32 + ((l >> 4) & 3) * 8];
#pragma unroll
    for (int ni = 0; ni < 4; ++ni)
      bf[ni] = *(const f16x8*)&Bs[(wn * 64 + ni * 16 + (l & 15)) * 32 + ((l >> 4) & 3) * 8];
#pragma unroll
    for (int mi = 0; mi < 4; ++mi)
#pragma unroll
      for (int ni = 0; ni < 4; ++ni)
        acc[mi][ni] = __builtin_amdgcn_mfma_f32_16x16x32_f16(af[mi], bf[ni], acc[mi][ni], 0, 0, 0);
    __syncthreads();
  }
  const int crow = wm * 64 + ((l >> 4) << 2);
  const int ccol = wn * 64 + (l & 15);
#pragma unroll
  for (int mi = 0; mi < 4; ++mi)
#pragma unroll
    for (int ni = 0; ni < 4; ++ni)
#pragma unroll
      for (int i = 0; i < 4; ++i)
        C[(size_t)(m0 + crow + mi * 16 + i) * N + n0 + ccol + ni * 16] = f2h(acc[mi][ni][i]);
}

// ---------------- persistent GRU recurrence (one layer, both dirs) ----------------
// 32 blocks: d = bid>>4, c = bid&15 (32 h-cols each). 256 thr = 4 waves:
// wm=w>>1 (row half), wq=w&1 (48-col half of the 96 gate-cols).
// h exchanged via hp (f16 fragment-packed, double-buffered by t parity).
__global__ __launch_bounds__(256) void gru_layer(const u16* __restrict__ gi,
                                                 const u16* __restrict__ WhhP,
                                                 const float* __restrict__ biasP,
                                                 float* __restrict__ hf,
                                                 u16* __restrict__ hp,
                                                 u32* __restrict__ y0,
                                                 int t0, int TC,
                                                 unsigned* __restrict__ bar) {
  const int bid = blockIdx.x;
  const int d = bid >> 4, c = bid & 15;
  const int tid = threadIdx.x;
  const int w = tid >> 6, l = tid & 63;
  const int wm = w >> 1, wq = w & 1;

  __shared__ u16 Wl[49152];    // 96 gate-cols x 512 k, frag-packed (98304 B)
  __shared__ float gh[12800];  // [128 rows][100 (96+4 pad)] f32 (51200 B)

  {  // stage this block's Whh slice into LDS once
    const u32x4* src = (const u32x4*)(WhhP + (size_t)(d * 16 + c) * 49152);
    u32x4* dst = (u32x4*)Wl;
#pragma unroll
    for (int i = 0; i < 24; ++i) dst[i * 256 + tid] = src[i * 256 + tid];
  }

  const int jp = tid & 15;  // j = 2*jp, 2*jp+1
  const int br = tid >> 4;  // 0..15
  float hreg[8][2];
  float bsr[2], bsz[2], bin[2], bhn[2];
#pragma unroll
  for (int v = 0; v < 2; ++v) {
    int j = c * 32 + 2 * jp + v;
    bsr[v] = biasP[(d * 4 + 0) * 512 + j];
    bsz[v] = biasP[(d * 4 + 1) * 512 + j];
    bin[v] = biasP[(d * 4 + 2) * 512 + j];
    bhn[v] = biasP[(d * 4 + 3) * 512 + j];
  }
#pragma unroll
  for (int bi = 0; bi < 8; ++bi) {
    int b = br + 16 * bi;
    hreg[bi][0] = hf[(d * 128 + b) * 512 + c * 32 + 2 * jp];
    hreg[bi][1] = hf[(d * 128 + b) * 512 + c * 32 + 2 * jp + 1];
  }
  __syncthreads();

  for (int t = t0; t < t0 + TC; ++t) {
    const u16* hr = hp + (size_t)((t & 1) * 2 + d) * 65536;
    f32x4 acc[4][3] = {};
#pragma unroll 4
    for (int kt = 0; kt < 16; ++kt) {
      f16x8 a[4];
#pragma unroll
      for (int mi = 0; mi < 4; ++mi)
        a[mi] = *(const f16x8*)&hr[((kt * 8 + wm * 4 + mi) * 64 + l) * 8];
#pragma unroll
      for (int qi = 0; qi < 3; ++qi) {
        f16x8 bf = *(const f16x8*)&Wl[(((wq * 3 + qi) * 16 + kt) * 64 + l) * 8];
#pragma unroll
        for (int mi = 0; mi < 4; ++mi)
          acc[mi][qi] = __builtin_amdgcn_mfma_f32_16x16x32_f16(a[mi], bf, acc[mi][qi], 0, 0, 0);
      }
    }
    // dump gate pre-activations to LDS for cross-wave exchange
#pragma unroll
    for (int mi = 0; mi < 4; ++mi)
#pragma unroll
      for (int qi = 0; qi < 3; ++qi) {
        int row = wm * 64 + mi * 16 + ((l >> 4) << 2);
        int q = (wq * 3 + qi) * 16 + (l & 15);
#pragma unroll
        for (int i = 0; i < 4; ++i) gh[(row + i) * 100 + q] = acc[mi][qi][i];
      }
    __syncthreads();

    u16* hw = hp + (size_t)(((t + 1) & 1) * 2 + d) * 65536;
    const int e0 = (2 * jp) & 7;
    const int lane2 = br | ((jp >> 2) << 4);
#pragma unroll
    for (int bi = 0; bi < 8; ++bi) {
      int b = br + 16 * bi;
      const float* g = &gh[b * 100];
      size_t girow = ((size_t)(t - t0) * 128 + b) * 3072 + d * 1536 + c * 32 + 2 * jp;
      u32 gr = *(const u32*)&gi[girow];
      u32 gz = *(const u32*)&gi[girow + 512];
      u32 gn = *(const u32*)&gi[girow + 1024];
      float hn[2];
#pragma unroll
      for (int v = 0; v < 2; ++v) {
        float gir = h2f((u16)(v ? (gr >> 16) : (gr & 0xffffu)));
        float giz = h2f((u16)(v ? (gz >> 16) : (gz & 0xffffu)));
        float gin = h2f((u16)(v ? (gn >> 16) : (gn & 0xffffu)));
        float r = sigm(gir + g[2 * jp + v] + bsr[v]);
        float z = sigm(giz + g[32 + 2 * jp + v] + bsz[v]);
        float n = tanh_(gin + bin[v] + r * (g[64 + 2 * jp + v] + bhn[v]));
        hn[v] = (1.f - z) * n + z * hreg[bi][v];
      }
      hreg[bi][0] = hn[0];
      hreg[bi][1] = hn[1];
      u32 pk = pack2(hn[0], hn[1]);
      *(u32*)&hw[((size_t)(c * 8 + bi) * 64 + lane2) * 8 + e0] = pk;
      if (y0) y0[((size_t)t * 128 + b) * 512 + d * 256 + c * 16 + jp] = pk;
    }
    gridbar(bar, 32);
  }
#pragma unroll
  for (int bi = 0; bi < 8; ++bi) {
    int b = br + 16 * bi;
    hf[(d * 128 + b) * 512 + c * 32 + 2 * jp] = hreg[bi][0];
    hf[(d * 128 + b) * 512 + c * 32 + 2 * jp + 1] = hreg[bi][1];
  }
}

// ---------------- classifier ----------------
__global__ __launch_bounds__(128) void classify(const float* __restrict__ hf,
                                                const float* __restrict__ Ws,
                                                const float* __restrict__ bs,
                                                float* __restrict__ out) {
  int b = threadIdx.x;
  float l0 = bs[0], l1 = bs[1];
#pragma unroll 8
  for (int j = 0; j < 512; ++j) {
    float v = hf[b * 512 + j];
    l0 = fmaf(v, Ws[j], l0);
    l1 = fmaf(v, Ws[1024 + j], l1);
  }
#pragma unroll 8
  for (int j = 0; j < 512; ++j) {
    float v = hf[(128 + b) * 512 + j];
    l0 = fmaf(v, Ws[512 + j], l0);
    l1 = fmaf(v, Ws[1536 + j], l1);
  }
  float m = fmaxf(l0, l1);
  float lse = m + __logf(__expf(l0 - m) + __expf(l1 - m));
  out[b * 2] = l0 - lse;
  out[b * 2 + 1] = l1 - lse;
}

extern "C" void kernel_launch(void* const* d_in, const int* in_sizes, int n_in,
                              void* d_out, int out_size, void* d_ws, size_t ws_size,
                              hipStream_t stream) {
  const int* X = (const int*)d_in[0];
  const float* emb = (const float*)d_in[1];
  const float* Wih0 = (const float*)d_in[2];
  const float* Whh0 = (const float*)d_in[3];
  const float* bih0 = (const float*)d_in[4];
  const float* bhh0 = (const float*)d_in[5];
  const float* Wih1 = (const float*)d_in[6];
  const float* Whh1 = (const float*)d_in[7];
  const float* bih1 = (const float*)d_in[8];
  const float* bhh1 = (const float*)d_in[9];
  const float* Ws = (const float*)d_in[10];
  const float* bs = (const float*)d_in[11];
  float* out = (float*)d_out;

  const int S = 400, B = 128;
  auto need = [&](int nc) -> size_t {
    size_t TC = (size_t)S / nc, R = TC * B;
    size_t sz = 0;
    sz += R * 3072 * 2;                       // giBuf
    sz += (size_t)S * B * 1024 * 2;           // y0
    sz += R * 320 * 2;                        // embC
    sz += (size_t)3072 * 320 * 2;             // B0p
    sz += (size_t)3072 * 1024 * 2;            // B1p
    sz += 2 * (size_t)1572864 * 2;            // WhhP x2 layers
    sz += 2 * (size_t)4096 * 4;               // biasP x2
    sz += 2 * (size_t)131072 * 4;             // hf x2
    sz += 2 * (size_t)262144 * 2;             // hp x2
    sz += 65536;                              // bars + align slack
    return sz;
  };
  int nc = 16;
  if (need(1) <= ws_size) nc = 1;
  else if (need(2) <= ws_size) nc = 2;
  else if (need(4) <= ws_size) nc = 4;
  else if (need(8) <= ws_size) nc = 8;
  const int TC = S / nc;
  const size_t R = (size_t)TC * B;

  char* p = (char*)d_ws;
  auto alloc = [&](size_t bytes) {
    char* q = p;
    p += (bytes + 255) & ~(size_t)255;
    return q;
  };
  u16* giBuf = (u16*)alloc(R * 3072 * 2);
  u16* y0 = (u16*)alloc((size_t)S * B * 1024 * 2);
  u16* embC = (u16*)alloc(R * 320 * 2);
  u16* B0p = (u16*)alloc((size_t)3072 * 320 * 2);
  u16* B1p = (u16*)alloc((size_t)3072 * 1024 * 2);
  u16* WhhP0 = (u16*)alloc((size_t)1572864 * 2);
  u16* WhhP1 = (u16*)alloc((size_t)1572864 * 2);
  float* biasP0 = (float*)alloc(4096 * 4);
  float* biasP1 = (float*)alloc(4096 * 4);
  float* hf0 = (float*)alloc(131072 * 4);
  float* hf1 = (float*)alloc(131072 * 4);
  u16* hp0 = (u16*)alloc(262144 * 2);
  u16* hp1 = (u16*)alloc(262144 * 2);
  unsigned* bar0 = (unsigned*)alloc(256);
  unsigned* bar1 = (unsigned*)alloc(256);

  hipMemsetAsync(hf0, 0, 131072 * 4, stream);
  hipMemsetAsync(hf1, 0, 131072 * 4, stream);
  hipMemsetAsync(hp0, 0, 262144 * 2, stream);
  hipMemsetAsync(hp1, 0, 262144 * 2, stream);
  hipMemsetAsync(bar0, 0, 256, stream);
  hipMemsetAsync(bar1, 0, 256, stream);

  pack_wih<<<3840, 256, 0, stream>>>(Wih0, B0p, 300, 320, 3072 * 320);
  pack_wih<<<12288, 256, 0, stream>>>(Wih1, B1p, 1024, 1024, 3072 * 1024);
  pack_whh<<<768, 256, 0, stream>>>(Whh0, WhhP0);
  pack_whh<<<768, 256, 0, stream>>>(Whh1, WhhP1);
  pack_bias<<<16, 256, 0, stream>>>(bih0, bhh0, biasP0);
  pack_bias<<<16, 256, 0, stream>>>(bih1, bhh1, biasP1);

  dim3 gg(24, (unsigned)(R / 128));
  for (int cix = 0; cix < nc; ++cix) {
    int t0 = cix * TC;
    int total = (int)(R * 160);
    gather_emb<<<(total + 255) / 256, 256, 0, stream>>>(X, emb, (u32*)embC, t0, total);
    gemm_f16<<<gg, 256, 0, stream>>>(embC, B0p, giBuf, 3072, 320);
    gru_layer<<<32, 256, 0, stream>>>(giBuf, WhhP0, biasP0, hf0, hp0, (u32*)y0, t0, TC, bar0);
  }
  for (int cix = 0; cix < nc; ++cix) {
    int t0 = cix * TC;
    gemm_f16<<<gg, 256, 0, stream>>>(y0 + (size_t)t0 * 128 * 1024, B1p, giBuf, 3072, 1024);
    gru_layer<<<32, 256, 0, stream>>>(giBuf, WhhP1, biasP1, hf1, hp1, (u32*)nullptr, t0, TC, bar1);
  }
  classify<<<1, 128, 0, stream>>>(hf1, Ws, bs, out);
}

// Round 2
// 7723.508 us; speedup vs baseline: 1.5771x; 1.5771x over previous
//
#include <hip/hip_runtime.h>

// SentimentAnalyzer: 2-layer (fake-)bidirectional GRU, S=400 B=128 H=512.
// v2: fence-free persistent recurrence. h exchanged via sc0/sc1 (L2-bypass)
// loads/stores at the coherence point; relaxed agent atomics for the barrier.
// 32x32x16 MFMA, all 3 gates of a column in one wave -> per-lane epilogue.

typedef unsigned int u32;
typedef unsigned short u16;
typedef __attribute__((ext_vector_type(8))) _Float16 f16x8;
typedef __attribute__((ext_vector_type(4))) float f32x4;
typedef __attribute__((ext_vector_type(16))) float f32x16;
typedef __attribute__((ext_vector_type(4))) u32 u32x4;

#define AS1 __attribute__((address_space(1)))
#define AS3 __attribute__((address_space(3)))

__device__ __forceinline__ void gl_lds16(const void* g, void* l) {
  __builtin_amdgcn_global_load_lds((AS1 void*)g, (AS3 void*)l, 16, 0, 0);
}
__device__ __forceinline__ u16 f2h(float f) {
  _Float16 h = (_Float16)f;
  return __builtin_bit_cast(u16, h);
}
__device__ __forceinline__ u32 pack2(float a, float b) {
  return (u32)f2h(a) | ((u32)f2h(b) << 16);
}
__device__ __forceinline__ float sigm(float x) {
  x = fminf(fmaxf(x, -30.f), 30.f);
  return 1.f / (1.f + __expf(-x));
}
__device__ __forceinline__ float tanh_(float x) {
  x = fminf(fmaxf(x, -15.f), 15.f);
  float e = __expf(2.f * x);
  return (e - 1.f) / (e + 1.f);
}
__device__ __forceinline__ f32x16 mfma32(f16x8 a, f16x8 b, f32x16 c) {
  return __builtin_amdgcn_mfma_f32_32x32x16_f16(a, b, c, 0, 0, 0);
}
// L2-bypass (coherence-point) load/store: sc0 sc1.
__device__ __forceinline__ f16x8 load_cc(const u16* sbase, u32 voff) {
  f16x8 r;
  asm volatile("global_load_dwordx4 %0, %1, %2 sc0 sc1"
               : "=v"(r) : "v"(voff), "s"(sbase) : "memory");
  return r;
}
__device__ __forceinline__ void store_cc16(u16* sbase, u32 voff, u32 val) {
  asm volatile("global_store_short %0, %1, %2 sc0 sc1"
               :: "v"(voff), "v"(val), "s"(sbase) : "memory");
}
__device__ __forceinline__ void wait_vm0() {
  asm volatile("s_waitcnt vmcnt(0)" ::: "memory");
}

// Fence-free generation barrier over 16 blocks (one direction).
__device__ __forceinline__ void gridbar16(unsigned* cnt, unsigned* gen) {
  __syncthreads();
  if (threadIdx.x == 0) {
    unsigned g = __hip_atomic_load(gen, __ATOMIC_RELAXED, __HIP_MEMORY_SCOPE_AGENT);
    unsigned a = __hip_atomic_fetch_add(cnt, 1u, __ATOMIC_RELAXED, __HIP_MEMORY_SCOPE_AGENT);
    if (a == 15u) {
      __hip_atomic_store(cnt, 0u, __ATOMIC_RELAXED, __HIP_MEMORY_SCOPE_AGENT);
      __hip_atomic_fetch_add(gen, 1u, __ATOMIC_RELAXED, __HIP_MEMORY_SCOPE_AGENT);
    } else {
      while (__hip_atomic_load(gen, __ATOMIC_RELAXED, __HIP_MEMORY_SCOPE_AGENT) == g)
        __builtin_amdgcn_s_sleep(1);
    }
  }
  __syncthreads();
}

// ---------------- pack kernels ----------------
__global__ __launch_bounds__(256) void pack_wih(const float* __restrict__ W,
                                                u16* __restrict__ out, int K, int Kp, int total) {
  int idx = blockIdx.x * 256 + threadIdx.x;
  if (idx >= total) return;
  int n = idx / Kp, k = idx - n * Kp;
  out[idx] = (k < K) ? f2h(W[(size_t)n * K + k]) : (u16)0;
}

// Whh -> 32x32x16 B-frag order: [dc(32)][g(3)][kt(32)][l(64)][e(8)]
// value = Whh[d][g*512 + c*32 + (l&31)][kt*16 + (l>>5)*8 + e]
__global__ __launch_bounds__(256) void pack_whh(const float* __restrict__ W,
                                                u16* __restrict__ out) {
  int idx = blockIdx.x * 256 + threadIdx.x;  // 196608 total, 8 u16 each
  int l = idx & 63;
  int kt = (idx >> 6) & 31;
  int rest = idx >> 11;
  int g = rest % 3, dc = rest / 3;
  int d = dc >> 4, c = dc & 15;
  int row = g * 512 + c * 32 + (l & 31);
  int k0 = kt * 16 + (l >> 5) * 8;
  const float* src = W + ((size_t)d * 1536 + row) * 512 + k0;
  u32* o = (u32*)(out + (size_t)idx * 8);
#pragma unroll
  for (int e2 = 0; e2 < 4; ++e2) o[e2] = pack2(src[2 * e2], src[2 * e2 + 1]);
}

// biasP[d][slot][512]: slot0=bih_r+bhh_r, 1=bih_z+bhh_z, 2=bih_n, 3=bhh_n
__global__ __launch_bounds__(256) void pack_bias(const float* __restrict__ bih,
                                                 const float* __restrict__ bhh,
                                                 float* __restrict__ out) {
  int idx = blockIdx.x * 256 + threadIdx.x;  // 4096
  int j = idx & 511;
  int slot = (idx >> 9) & 3;
  int d = idx >> 11;
  float v;
  if (slot == 0) v = bih[d * 1536 + j] + bhh[d * 1536 + j];
  else if (slot == 1) v = bih[d * 1536 + 512 + j] + bhh[d * 1536 + 512 + j];
  else if (slot == 2) v = bih[d * 1536 + 1024 + j];
  else v = bhh[d * 1536 + 1024 + j];
  out[idx] = v;
}

__global__ __launch_bounds__(256) void gather_emb(const int* __restrict__ X,
                                                  const float* __restrict__ emb,
                                                  u32* __restrict__ out, int t0, int total) {
  int idx = blockIdx.x * 256 + threadIdx.x;
  if (idx >= total) return;
  int r = idx / 160, kp = idx - r * 160;
  int k = kp * 2;
  int tok = X[t0 * 128 + r];
  float v0 = (k < 300) ? emb[(size_t)tok * 300 + k] : 0.f;
  float v1 = (k < 299) ? emb[(size_t)tok * 300 + k + 1] : 0.f;
  out[idx] = pack2(v0, v1);
}

// ---- big GEMM: giPack = A[M][K] * B[N=3072][K]^T, writes gru-native pack ----
// pack idx: [t_rel][d2][c16][w4][n6][lane64][e8] u16,
//   b=row&127: w=b>>5, reg=(b&3)|(((b>>3)&3)<<2), l5=(b>>2)&1
//   col: d, g=cc>>9, c=(cc>>5)&15, jj=cc&31; lane=jj|(l5<<5); s=g*16+reg
__global__ __launch_bounds__(256) void gemm_f16(const u16* __restrict__ A,
                                                const u16* __restrict__ B,
                                                u16* __restrict__ giP, int K) {
  __shared__ u16 As[4096];
  __shared__ u16 Bs[4096];
  const int tid = threadIdx.x;
  const int w = tid >> 6, l = tid & 63;
  const long m0 = (long)blockIdx.y << 7;
  const long n0 = (long)blockIdx.x << 7;
  const int wm = w >> 1, wn = w & 1;
  f32x4 acc[4][4] = {};

  const int srow = w * 16 + (l >> 2);
  const int scol = (l & 3) * 8;
  const u16* ga = A + (m0 + srow) * K + scol;
  const u16* gb = B + (n0 + srow) * K + scol;
  u16* lA = &As[w * 512];
  u16* lB = &Bs[w * 512];

  for (int k0 = 0; k0 < K; k0 += 32) {
    gl_lds16(ga + k0, lA);
    gl_lds16(ga + 64 * K + k0, lA + 2048);
    gl_lds16(gb + k0, lB);
    gl_lds16(gb + 64 * K + k0, lB + 2048);
    __syncthreads();
    f16x8 af[4], bf[4];
#pragma unroll
    for (int mi = 0; mi < 4; ++mi)
      af[mi] = *(const f16x8*)&As[(wm * 64 + mi * 16 + (l & 15)) * 32 + ((l >> 4) & 3) * 8];
#pragma unroll
    for (int ni = 0; ni < 4; ++ni)
      bf[ni] = *(const f16x8*)&Bs[(wn * 64 + ni * 16 + (l & 15)) * 32 + ((l >> 4) & 3) * 8];
#pragma unroll
    for (int mi = 0; mi < 4; ++mi)
#pragma unroll
      for (int ni = 0; ni < 4; ++ni)
        acc[mi][ni] = __builtin_amdgcn_mfma_f32_16x16x32_f16(af[mi], bf[ni], acc[mi][ni], 0, 0, 0);
    __syncthreads();
  }
  const int crow = wm * 64 + ((l >> 4) << 2);
  const int ccol = wn * 64 + (l & 15);
#pragma unroll
  for (int mi = 0; mi < 4; ++mi)
#pragma unroll
    for (int ni = 0; ni < 4; ++ni)
#pragma unroll
      for (int i = 0; i < 4; ++i) {
        int grow = (int)m0 + crow + mi * 16 + i;
        int col = (int)n0 + ccol + ni * 16;
        int t_rel = grow >> 7, b = grow & 127;
        int dd = (col >= 1536) ? 1 : 0;
        int cc2 = col - dd * 1536;
        int g = cc2 >> 9, ch = (cc2 >> 5) & 15, jj = cc2 & 31;
        int wt = b >> 5, reg = (b & 3) | (((b >> 3) & 3) << 2), l5 = (b >> 2) & 1;
        int lt = jj | (l5 << 5);
        int s = g * 16 + reg, n2 = s >> 3, e = s & 7;
        size_t idx = (((((size_t)t_rel * 2 + dd) * 16 + ch) * 4 + wt) * 6 + n2) * 512 + lt * 8 + e;
        giP[idx] = f2h(acc[mi][ni][i]);
      }
}

// ---------------- persistent GRU recurrence (one layer, both dirs) ----------------
// 32 blocks: d=bid>>4, c=bid&15 (32 h-cols). 4 waves x 32 rows. Per wave:
// 1 row-frag x 3 gate col-frags x 32 kt = 96 MFMA (32x32x16). Epilogue per-lane.
// hp layout: [parity][d2][w4][kt32][l64][e8] f16 = h[w*32+(l&31)][kt*16+(l>>5)*8+e]
__global__ __launch_bounds__(256, 1) void gru_layer(const u16* __restrict__ gi,
                                                    const u16* __restrict__ WhhP,
                                                    const float* __restrict__ biasP,
                                                    float* __restrict__ hf,
                                                    u16* __restrict__ hp,
                                                    u16* __restrict__ y0,
                                                    int t0, int TC,
                                                    unsigned* __restrict__ bar) {
  const int bid = blockIdx.x;
  const int d = bid >> 4, c = bid & 15;
  const int tid = threadIdx.x;
  const int w = tid >> 6, l = tid & 63;

  __shared__ u16 Wl[49152];  // [g3][kt32][l64][e8], 96 KiB

  {  // stage this block's Whh slice
    const u32x4* src = (const u32x4*)(WhhP + (size_t)(d * 16 + c) * 49152);
    u32x4* dst = (u32x4*)Wl;
#pragma unroll
    for (int i = 0; i < 24; ++i) dst[i * 256 + tid] = src[i * 256 + tid];
  }

  const int jcol = c * 32 + (l & 31);
  const float bsr = biasP[(d * 4 + 0) * 512 + jcol];
  const float bsz = biasP[(d * 4 + 1) * 512 + jcol];
  const float bin = biasP[(d * 4 + 2) * 512 + jcol];
  const float bhn = biasP[(d * 4 + 3) * 512 + jcol];

  const int l5 = l >> 5;
  float hreg[16];
#pragma unroll
  for (int r = 0; r < 16; ++r) {
    int row = (r & 3) + 8 * (r >> 2) + 4 * l5;
    hreg[r] = hf[((size_t)d * 128 + w * 32 + row) * 512 + jcol];
  }
  __syncthreads();

  // first gi prefetch (normal cached loads; giPack written by gemm)
  f16x8 giv[6];
  {
    const u16* gp = gi + ((((size_t)0 * 2 + d) * 16 + c) * 4 + w) * 6 * 512 + l * 8;
#pragma unroll
    for (int n2 = 0; n2 < 6; ++n2) giv[n2] = *(const f16x8*)(gp + n2 * 512);
  }
  wait_vm0();  // baseline: vmem queue empty before counted waits

  unsigned* cnt = bar + d * 32;
  unsigned* gen = bar + d * 32 + 16;
  const u32 aoffbase = (u32)((d * 4 + w) * 32768 + l * 16);  // bytes
  const int ktj = jcol >> 4;
  const int lb5 = ((l >> 3) & 1) << 5;
  const int ej = l & 7;

  for (int t = t0; t < t0 + TC; ++t) {
    const u16* hrb = hp + (size_t)(t & 1) * 131072;
    // issue all 32 A-frag loads (L2-bypass)
    f16x8 a[32];
#pragma unroll
    for (int kt = 0; kt < 32; ++kt) a[kt] = load_cc(hrb, aoffbase + (u32)kt * 1024u);

    f32x16 accR = {}, accZ = {}, accN = {};
#pragma unroll
    for (int g4 = 0; g4 < 8; ++g4) {
      asm volatile("s_waitcnt vmcnt(%0)" ::"n"(28 - 4 * 8 / 2) : "memory");  // placeholder replaced below
      // (real wait emitted per-group below)
      break;
    }
    // 8 groups of 4 kt with counted waits
#pragma unroll
    for (int g4 = 0; g4 < 8; ++g4) {
      switch (g4) {
        case 0: asm volatile("s_waitcnt vmcnt(28)" ::: "memory"); break;
        case 1: asm volatile("s_waitcnt vmcnt(24)" ::: "memory"); break;
        case 2: asm volatile("s_waitcnt vmcnt(20)" ::: "memory"); break;
        case 3: asm volatile("s_waitcnt vmcnt(16)" ::: "memory"); break;
        case 4: asm volatile("s_waitcnt vmcnt(12)" ::: "memory"); break;
        case 5: asm volatile("s_waitcnt vmcnt(8)" ::: "memory"); break;
        case 6: asm volatile("s_waitcnt vmcnt(4)" ::: "memory"); break;
        default: asm volatile("s_waitcnt vmcnt(0)" ::: "memory"); break;
      }
      __builtin_amdgcn_sched_barrier(0);
#pragma unroll
      for (int kk = 0; kk < 4; ++kk) {
        int kt = g4 * 4 + kk;
        f16x8 b0 = *(const f16x8*)&Wl[(0 * 32 + kt) * 512 + l * 8];
        f16x8 b1 = *(const f16x8*)&Wl[(1 * 32 + kt) * 512 + l * 8];
        f16x8 b2 = *(const f16x8*)&Wl[(2 * 32 + kt) * 512 + l * 8];
        accR = mfma32(a[kt], b0, accR);
        accZ = mfma32(a[kt], b1, accZ);
        accN = mfma32(a[kt], b2, accN);
      }
    }

    // per-lane epilogue
    u16* hwb = hp + (size_t)((t + 1) & 1) * 131072;
#pragma unroll
    for (int r = 0; r < 16; ++r) {
      float gr = (float)giv[r >> 3][r & 7];
      float gz = (float)giv[2 + (r >> 3)][r & 7];
      float gn = (float)giv[4 + (r >> 3)][r & 7];
      float rr = sigm(gr + accR[r] + bsr);
      float zz = sigm(gz + accZ[r] + bsz);
      float nn = tanh_(gn + bin + rr * (accN[r] + bhn));
      float h = (1.f - zz) * nn + zz * hreg[r];
      hreg[r] = h;
      int row = (r & 3) + 8 * (r >> 2) + 4 * l5;
      u32 voff = (u32)(((((d * 4 + w) * 32 + ktj) * 64 + (row | lb5)) * 8 + ej) * 2);
      store_cc16(hwb, voff, (u32)f2h(h));
      if (y0) {
        int b = w * 32 + row;
        y0[((size_t)t * 128 + b) * 1024 + d * 512 + jcol] = f2h(h);
      }
    }

    wait_vm0();  // h-stores at coherence point before arrive

    if (t + 1 < t0 + TC) {
      // prefetch next gi across the barrier
      const u16* gp = gi + ((((size_t)(t + 1 - t0) * 2 + d) * 16 + c) * 4 + w) * 6 * 512 + l * 8;
#pragma unroll
      for (int n2 = 0; n2 < 6; ++n2) giv[n2] = *(const f16x8*)(gp + n2 * 512);
      gridbar16(cnt, gen);
    }
  }

#pragma unroll
  for (int r = 0; r < 16; ++r) {
    int row = (r & 3) + 8 * (r >> 2) + 4 * l5;
    hf[((size_t)d * 128 + w * 32 + row) * 512 + jcol] = hreg[r];
  }
  wait_vm0();
}

// ---------------- classifier ----------------
__global__ __launch_bounds__(128) void classify(const float* __restrict__ hf,
                                                const float* __restrict__ Ws,
                                                const float* __restrict__ bs,
                                                float* __restrict__ out) {
  int b = threadIdx.x;
  float l0 = bs[0], l1 = bs[1];
#pragma unroll 8
  for (int j = 0; j < 512; ++j) {
    float v = hf[b * 512 + j];
    l0 = fmaf(v, Ws[j], l0);
    l1 = fmaf(v, Ws[1024 + j], l1);
  }
#pragma unroll 8
  for (int j = 0; j < 512; ++j) {
    float v = hf[(128 + b) * 512 + j];
    l0 = fmaf(v, Ws[512 + j], l0);
    l1 = fmaf(v, Ws[1536 + j], l1);
  }
  float m = fmaxf(l0, l1);
  float lse = m + __logf(__expf(l0 - m) + __expf(l1 - m));
  out[b * 2] = l0 - lse;
  out[b * 2 + 1] = l1 - lse;
}

extern "C" void kernel_launch(void* const* d_in, const int* in_sizes, int n_in,
                              void* d_out, int out_size, void* d_ws, size_t ws_size,
                              hipStream_t stream) {
  const int* X = (const int*)d_in[0];
  const float* emb = (const float*)d_in[1];
  const float* Wih0 = (const float*)d_in[2];
  const float* Whh0 = (const float*)d_in[3];
  const float* bih0 = (const float*)d_in[4];
  const float* bhh0 = (const float*)d_in[5];
  const float* Wih1 = (const float*)d_in[6];
  const float* Whh1 = (const float*)d_in[7];
  const float* bih1 = (const float*)d_in[8];
  const float* bhh1 = (const float*)d_in[9];
  const float* Ws = (const float*)d_in[10];
  const float* bs = (const float*)d_in[11];
  float* out = (float*)d_out;

  const int S = 400, B = 128;
  auto need = [&](int nc) -> size_t {
    size_t TC = (size_t)S / nc, R = TC * B;
    size_t sz = 0;
    sz += R * 3072 * 2;              // giPack
    sz += (size_t)S * B * 1024 * 2;  // y0
    sz += R * 320 * 2;               // embC
    sz += (size_t)3072 * 320 * 2;    // B0p
    sz += (size_t)3072 * 1024 * 2;   // B1p
    sz += 2 * (size_t)1572864 * 2;   // WhhP x2
    sz += 2 * (size_t)4096 * 4;      // biasP x2
    sz += 2 * (size_t)131072 * 4;    // hf x2
    sz += 2 * (size_t)262144 * 2;    // hp x2
    sz += 65536;
    return sz;
  };
  int nc = 16;
  if (need(1) <= ws_size) nc = 1;
  else if (need(2) <= ws_size) nc = 2;
  else if (need(4) <= ws_size) nc = 4;
  else if (need(8) <= ws_size) nc = 8;
  const int TC = S / nc;
  const size_t R = (size_t)TC * B;

  char* p = (char*)d_ws;
  auto alloc = [&](size_t bytes) {
    char* q = p;
    p += (bytes + 255) & ~(size_t)255;
    return q;
  };
  u16* giPack = (u16*)alloc(R * 3072 * 2);
  u16* y0 = (u16*)alloc((size_t)S * B * 1024 * 2);
  u16* embC = (u16*)alloc(R * 320 * 2);
  u16* B0p = (u16*)alloc((size_t)3072 * 320 * 2);
  u16* B1p = (u16*)alloc((size_t)3072 * 1024 * 2);
  u16* WhhP0 = (u16*)alloc((size_t)1572864 * 2);
  u16* WhhP1 = (u16*)alloc((size_t)1572864 * 2);
  float* biasP0 = (float*)alloc(4096 * 4);
  float* biasP1 = (float*)alloc(4096 * 4);
  float* hf0 = (float*)alloc(131072 * 4);
  float* hf1 = (float*)alloc(131072 * 4);
  u16* hp0 = (u16*)alloc(262144 * 2);
  u16* hp1 = (u16*)alloc(262144 * 2);
  unsigned* bar0 = (unsigned*)alloc(256);
  unsigned* bar1 = (unsigned*)alloc(256);

  hipMemsetAsync(hf0, 0, 131072 * 4, stream);
  hipMemsetAsync(hf1, 0, 131072 * 4, stream);
  hipMemsetAsync(hp0, 0, 262144 * 2, stream);
  hipMemsetAsync(hp1, 0, 262144 * 2, stream);
  hipMemsetAsync(bar0, 0, 256, stream);
  hipMemsetAsync(bar1, 0, 256, stream);

  pack_wih<<<3840, 256, 0, stream>>>(Wih0, B0p, 300, 320, 3072 * 320);
  pack_wih<<<12288, 256, 0, stream>>>(Wih1, B1p, 1024, 1024, 3072 * 1024);
  pack_whh<<<768, 256, 0, stream>>>(Whh0, WhhP0);
  pack_whh<<<768, 256, 0, stream>>>(Whh1, WhhP1);
  pack_bias<<<16, 256, 0, stream>>>(bih0, bhh0, biasP0);
  pack_bias<<<16, 256, 0, stream>>>(bih1, bhh1, biasP1);

  dim3 gg(24, (unsigned)(R / 128));
  for (int cix = 0; cix < nc; ++cix) {
    int t0 = cix * TC;
    int total = (int)(R * 160);
    gather_emb<<<(total + 255) / 256, 256, 0, stream>>>(X, emb, (u32*)embC, t0, total);
    gemm_f16<<<gg, 256, 0, stream>>>(embC, B0p, giPack, 320);
    gru_layer<<<32, 256, 0, stream>>>(giPack, WhhP0, biasP0, hf0, hp0, y0, t0, TC, bar0);
  }
  for (int cix = 0; cix < nc; ++cix) {
    int t0 = cix * TC;
    gemm_f16<<<gg, 256, 0, stream>>>(y0 + (size_t)t0 * 128 * 1024, B1p, giPack, 1024);
    gru_layer<<<32, 256, 0, stream>>>(giPack, WhhP1, biasP1, hf1, hp1, (u16*)nullptr, t0, TC, bar1);
  }
  classify<<<1, 128, 0, stream>>>(hf1, Ws, bs, out);
}

// Round 3
// 6710.264 us; speedup vs baseline: 1.8153x; 1.1510x over previous
//
#include <hip/hip_runtime.h>

// SentimentAnalyzer: 2-layer (fake-)bidirectional GRU, S=400 B=128 H=512.
// v3: flag-based dataflow sync replaces the atomic generation barrier.
// Producer publishes h(t+1) via sc0/sc1 stores -> vmcnt(0) -> syncthreads ->
// one flag store. Consumers poll one 64B flag line (16 lanes + __all).
// h ring depth 4 (skew bound <= 2 slots). No fences anywhere.

typedef unsigned int u32;
typedef unsigned short u16;
typedef __attribute__((ext_vector_type(8))) _Float16 f16x8;
typedef __attribute__((ext_vector_type(4))) float f32x4;
typedef __attribute__((ext_vector_type(16))) float f32x16;
typedef __attribute__((ext_vector_type(4))) u32 u32x4;

#define AS1 __attribute__((address_space(1)))
#define AS3 __attribute__((address_space(3)))

__device__ __forceinline__ void gl_lds16(const void* g, void* l) {
  __builtin_amdgcn_global_load_lds((AS1 void*)g, (AS3 void*)l, 16, 0, 0);
}
__device__ __forceinline__ u16 f2h(float f) {
  _Float16 h = (_Float16)f;
  return __builtin_bit_cast(u16, h);
}
__device__ __forceinline__ u32 pack2(float a, float b) {
  return (u32)f2h(a) | ((u32)f2h(b) << 16);
}
__device__ __forceinline__ float sigm(float x) {
  x = fminf(fmaxf(x, -30.f), 30.f);
  return 1.f / (1.f + __expf(-x));
}
__device__ __forceinline__ float tanh_(float x) {
  x = fminf(fmaxf(x, -15.f), 15.f);
  float e = __expf(2.f * x);
  return (e - 1.f) / (e + 1.f);
}
__device__ __forceinline__ f32x16 mfma32(f16x8 a, f16x8 b, f32x16 c) {
  return __builtin_amdgcn_mfma_f32_32x32x16_f16(a, b, c, 0, 0, 0);
}
// L2-bypass (coherence-point) load/store: sc0 sc1.
__device__ __forceinline__ f16x8 load_cc(const u16* sbase, u32 voff) {
  f16x8 r;
  asm volatile("global_load_dwordx4 %0, %1, %2 sc0 sc1"
               : "=v"(r) : "v"(voff), "s"(sbase) : "memory");
  return r;
}
__device__ __forceinline__ void store_cc16(u16* sbase, u32 voff, u32 val) {
  asm volatile("global_store_short %0, %1, %2 sc0 sc1"
               :: "v"(voff), "v"(val), "s"(sbase) : "memory");
}
__device__ __forceinline__ void wait_vm0() {
  asm volatile("s_waitcnt vmcnt(0)" ::: "memory");
}

// ---------------- pack kernels ----------------
__global__ __launch_bounds__(256) void pack_wih(const float* __restrict__ W,
                                                u16* __restrict__ out, int K, int Kp, int total) {
  int idx = blockIdx.x * 256 + threadIdx.x;
  if (idx >= total) return;
  int n = idx / Kp, k = idx - n * Kp;
  out[idx] = (k < K) ? f2h(W[(size_t)n * K + k]) : (u16)0;
}

// Whh -> 32x32x16 B-frag order: [dc(32)][g(3)][kt(32)][l(64)][e(8)]
// value = Whh[d][g*512 + c*32 + (l&31)][kt*16 + (l>>5)*8 + e]
__global__ __launch_bounds__(256) void pack_whh(const float* __restrict__ W,
                                                u16* __restrict__ out) {
  int idx = blockIdx.x * 256 + threadIdx.x;  // 196608 total, 8 u16 each
  int l = idx & 63;
  int kt = (idx >> 6) & 31;
  int rest = idx >> 11;
  int g = rest % 3, dc = rest / 3;
  int d = dc >> 4, c = dc & 15;
  int row = g * 512 + c * 32 + (l & 31);
  int k0 = kt * 16 + (l >> 5) * 8;
  const float* src = W + ((size_t)d * 1536 + row) * 512 + k0;
  u32* o = (u32*)(out + (size_t)idx * 8);
#pragma unroll
  for (int e2 = 0; e2 < 4; ++e2) o[e2] = pack2(src[2 * e2], src[2 * e2 + 1]);
}

// biasP[d][slot][512]: slot0=bih_r+bhh_r, 1=bih_z+bhh_z, 2=bih_n, 3=bhh_n
__global__ __launch_bounds__(256) void pack_bias(const float* __restrict__ bih,
                                                 const float* __restrict__ bhh,
                                                 float* __restrict__ out) {
  int idx = blockIdx.x * 256 + threadIdx.x;  // 4096
  int j = idx & 511;
  int slot = (idx >> 9) & 3;
  int d = idx >> 11;
  float v;
  if (slot == 0) v = bih[d * 1536 + j] + bhh[d * 1536 + j];
  else if (slot == 1) v = bih[d * 1536 + 512 + j] + bhh[d * 1536 + 512 + j];
  else if (slot == 2) v = bih[d * 1536 + 1024 + j];
  else v = bhh[d * 1536 + 1024 + j];
  out[idx] = v;
}

__global__ __launch_bounds__(256) void gather_emb(const int* __restrict__ X,
                                                  const float* __restrict__ emb,
                                                  u32* __restrict__ out, int t0, int total) {
  int idx = blockIdx.x * 256 + threadIdx.x;
  if (idx >= total) return;
  int r = idx / 160, kp = idx - r * 160;
  int k = kp * 2;
  int tok = X[t0 * 128 + r];
  float v0 = (k < 300) ? emb[(size_t)tok * 300 + k] : 0.f;
  float v1 = (k < 299) ? emb[(size_t)tok * 300 + k + 1] : 0.f;
  out[idx] = pack2(v0, v1);
}

// ---- big GEMM: giPack = A[M][K] * B[N=3072][K]^T, writes gru-native pack ----
__global__ __launch_bounds__(256) void gemm_f16(const u16* __restrict__ A,
                                                const u16* __restrict__ B,
                                                u16* __restrict__ giP, int K) {
  __shared__ u16 As[4096];
  __shared__ u16 Bs[4096];
  const int tid = threadIdx.x;
  const int w = tid >> 6, l = tid & 63;
  const long m0 = (long)blockIdx.y << 7;
  const long n0 = (long)blockIdx.x << 7;
  const int wm = w >> 1, wn = w & 1;
  f32x4 acc[4][4] = {};

  const int srow = w * 16 + (l >> 2);
  const int scol = (l & 3) * 8;
  const u16* ga = A + (m0 + srow) * K + scol;
  const u16* gb = B + (n0 + srow) * K + scol;
  u16* lA = &As[w * 512];
  u16* lB = &Bs[w * 512];

  for (int k0 = 0; k0 < K; k0 += 32) {
    gl_lds16(ga + k0, lA);
    gl_lds16(ga + 64 * K + k0, lA + 2048);
    gl_lds16(gb + k0, lB);
    gl_lds16(gb + 64 * K + k0, lB + 2048);
    __syncthreads();
    f16x8 af[4], bf[4];
#pragma unroll
    for (int mi = 0; mi < 4; ++mi)
      af[mi] = *(const f16x8*)&As[(wm * 64 + mi * 16 + (l & 15)) * 32 + ((l >> 4) & 3) * 8];
#pragma unroll
    for (int ni = 0; ni < 4; ++ni)
      bf[ni] = *(const f16x8*)&Bs[(wn * 64 + ni * 16 + (l & 15)) * 32 + ((l >> 4) & 3) * 8];
#pragma unroll
    for (int mi = 0; mi < 4; ++mi)
#pragma unroll
      for (int ni = 0; ni < 4; ++ni)
        acc[mi][ni] = __builtin_amdgcn_mfma_f32_16x16x32_f16(af[mi], bf[ni], acc[mi][ni], 0, 0, 0);
    __syncthreads();
  }
  const int crow = wm * 64 + ((l >> 4) << 2);
  const int ccol = wn * 64 + (l & 15);
#pragma unroll
  for (int mi = 0; mi < 4; ++mi)
#pragma unroll
    for (int ni = 0; ni < 4; ++ni)
#pragma unroll
      for (int i = 0; i < 4; ++i) {
        int grow = (int)m0 + crow + mi * 16 + i;
        int col = (int)n0 + ccol + ni * 16;
        int t_rel = grow >> 7, b = grow & 127;
        int dd = (col >= 1536) ? 1 : 0;
        int cc2 = col - dd * 1536;
        int g = cc2 >> 9, ch = (cc2 >> 5) & 15, jj = cc2 & 31;
        int wt = b >> 5, reg = (b & 3) | (((b >> 3) & 3) << 2), l5 = (b >> 2) & 1;
        int lt = jj | (l5 << 5);
        int s = g * 16 + reg, n2 = s >> 3, e = s & 7;
        size_t idx = (((((size_t)t_rel * 2 + dd) * 16 + ch) * 4 + wt) * 6 + n2) * 512 + lt * 8 + e;
        giP[idx] = f2h(acc[mi][ni][i]);
      }
}

// ---------------- persistent GRU recurrence (one layer, both dirs) ----------------
// 32 blocks: d=bid>>4, c=bid&15 (32 h-cols). 4 waves x 32 rows. Per wave:
// 1 row-frag x 3 gate col-frags x 32 kt = 96 MFMA (32x32x16). Per-lane epilogue.
// hp ring: 4 slots x [d2][w4][kt32][l64][e8] f16. Flags: [d2][slot4][16] u32,
// flag value == t means "h(t) published". Poll: 16 lanes read one 64B line.
__global__ __launch_bounds__(256, 1) void gru_layer(const u16* __restrict__ gi,
                                                    const u16* __restrict__ WhhP,
                                                    const float* __restrict__ biasP,
                                                    float* __restrict__ hf,
                                                    u16* __restrict__ hp,
                                                    u16* __restrict__ y0,
                                                    u32* __restrict__ flags,
                                                    int t0, int TC) {
  const int bid = blockIdx.x;
  const int d = bid >> 4, c = bid & 15;
  const int tid = threadIdx.x;
  const int w = tid >> 6, l = tid & 63;

  __shared__ u16 Wl[49152];  // [g3][kt32][l64][e8], 96 KiB

  {  // stage this block's Whh slice
    const u32x4* src = (const u32x4*)(WhhP + (size_t)(d * 16 + c) * 49152);
    u32x4* dst = (u32x4*)Wl;
#pragma unroll
    for (int i = 0; i < 24; ++i) dst[i * 256 + tid] = src[i * 256 + tid];
  }

  const int jcol = c * 32 + (l & 31);
  const float bsr = biasP[(d * 4 + 0) * 512 + jcol];
  const float bsz = biasP[(d * 4 + 1) * 512 + jcol];
  const float bin = biasP[(d * 4 + 2) * 512 + jcol];
  const float bhn = biasP[(d * 4 + 3) * 512 + jcol];

  const int l5 = l >> 5;
  float hreg[16];
#pragma unroll
  for (int r = 0; r < 16; ++r) {
    int row = (r & 3) + 8 * (r >> 2) + 4 * l5;
    hreg[r] = hf[((size_t)d * 128 + w * 32 + row) * 512 + jcol];
  }
  __syncthreads();

  // prefetch gi(t0)
  f16x8 giv[6];
  {
    const u16* gp = gi + (((size_t)(0 * 2 + d) * 16 + c) * 4 + w) * 3072 + l * 8;
#pragma unroll
    for (int n2 = 0; n2 < 6; ++n2) giv[n2] = *(const f16x8*)(gp + n2 * 512);
  }

  const u32 aoffbase = (u32)((d * 4 + w) * 32768 + l * 16);  // bytes
  const int ktj = jcol >> 4;
  const int lb5 = ((l >> 3) & 1) << 5;
  const int ej = l & 7;
  const u32 foff = (u32)((l & 15) * 4);

  for (int t = t0; t < t0 + TC; ++t) {
    // ---- poll flags(t): all 16 producer slices of this direction ----
    {
      const u32* fb = flags + (size_t)(d * 4 + (t & 3)) * 16;
      for (;;) {
        u32 v;
        asm volatile("global_load_dword %0, %1, %2 sc0 sc1\n\ts_waitcnt vmcnt(0)"
                     : "=v"(v) : "v"(foff), "s"(fb) : "memory");
        if (__all((int)(v >= (u32)t))) break;
      }
    }

    // ---- issue all 32 A-frag loads (L2-bypass) ----
    const u16* hrb = hp + (size_t)(t & 3) * 131072;
    f16x8 a[32];
#pragma unroll
    for (int kt = 0; kt < 32; ++kt) a[kt] = load_cc(hrb, aoffbase + (u32)kt * 1024u);

    f32x16 accR = {}, accZ = {}, accN = {};
    // 8 groups of 4 kt with counted waits (exactly 32 vmem ops outstanding)
#pragma unroll
    for (int g4 = 0; g4 < 8; ++g4) {
      switch (g4) {
        case 0: asm volatile("s_waitcnt vmcnt(28)" ::: "memory"); break;
        case 1: asm volatile("s_waitcnt vmcnt(24)" ::: "memory"); break;
        case 2: asm volatile("s_waitcnt vmcnt(20)" ::: "memory"); break;
        case 3: asm volatile("s_waitcnt vmcnt(16)" ::: "memory"); break;
        case 4: asm volatile("s_waitcnt vmcnt(12)" ::: "memory"); break;
        case 5: asm volatile("s_waitcnt vmcnt(8)" ::: "memory"); break;
        case 6: asm volatile("s_waitcnt vmcnt(4)" ::: "memory"); break;
        default: asm volatile("s_waitcnt vmcnt(0)" ::: "memory"); break;
      }
      __builtin_amdgcn_sched_barrier(0);
#pragma unroll
      for (int kk = 0; kk < 4; ++kk) {
        int kt = g4 * 4 + kk;
        f16x8 b0 = *(const f16x8*)&Wl[(0 * 32 + kt) * 512 + l * 8];
        f16x8 b1 = *(const f16x8*)&Wl[(1 * 32 + kt) * 512 + l * 8];
        f16x8 b2 = *(const f16x8*)&Wl[(2 * 32 + kt) * 512 + l * 8];
        accR = mfma32(a[kt], b0, accR);
        accZ = mfma32(a[kt], b1, accZ);
        accN = mfma32(a[kt], b2, accN);
      }
    }

    // ---- per-lane epilogue + h/y0 stores ----
    u16* hwb = hp + (size_t)((t + 1) & 3) * 131072;
#pragma unroll
    for (int r = 0; r < 16; ++r) {
      float gr = (float)giv[r >> 3][r & 7];
      float gz = (float)giv[2 + (r >> 3)][r & 7];
      float gn = (float)giv[4 + (r >> 3)][r & 7];
      float rr = sigm(gr + accR[r] + bsr);
      float zz = sigm(gz + accZ[r] + bsz);
      float nn = tanh_(gn + bin + rr * (accN[r] + bhn));
      float h = (1.f - zz) * nn + zz * hreg[r];
      hreg[r] = h;
      int row = (r & 3) + 8 * (r >> 2) + 4 * l5;
      u32 voff = (u32)(((((d * 4 + w) * 32 + ktj) * 64 + (row | lb5)) * 8 + ej) * 2);
      store_cc16(hwb, voff, (u32)f2h(h));
      if (y0) {
        int b = w * 32 + row;
        y0[((size_t)t * 128 + b) * 1024 + d * 512 + jcol] = f2h(h);
      }
    }

    // ---- prefetch next gi (overlaps the store drain) ----
    {
      int rel = t + 1 - t0;
      if (rel >= TC) rel = TC - 1;
      const u16* gp = gi + (((size_t)rel * 2 + d) * 16 + c) * 4 * 3072 + (size_t)w * 3072 + l * 8;
#pragma unroll
      for (int n2 = 0; n2 < 6; ++n2) giv[n2] = *(const f16x8*)(gp + n2 * 512);
    }

    // ---- publish: drain stores, block-wide rendezvous, one flag store ----
    asm volatile("s_waitcnt vmcnt(0)" ::: "memory");
    __syncthreads();
    if (tid == 0) {
      u32* fw = flags + (size_t)(d * 4 + ((t + 1) & 3)) * 16 + c;
      u32 val = (u32)(t + 1);
      asm volatile("global_store_dword %0, %1, %2 sc0 sc1"
                   :: "v"(0u), "v"(val), "s"(fw) : "memory");
    }
  }

#pragma unroll
  for (int r = 0; r < 16; ++r) {
    int row = (r & 3) + 8 * (r >> 2) + 4 * l5;
    hf[((size_t)d * 128 + w * 32 + row) * 512 + jcol] = hreg[r];
  }
  wait_vm0();
}

// ---------------- classifier ----------------
__global__ __launch_bounds__(128) void classify(const float* __restrict__ hf,
                                                const float* __restrict__ Ws,
                                                const float* __restrict__ bs,
                                                float* __restrict__ out) {
  int b = threadIdx.x;
  float l0 = bs[0], l1 = bs[1];
#pragma unroll 8
  for (int j = 0; j < 512; ++j) {
    float v = hf[b * 512 + j];
    l0 = fmaf(v, Ws[j], l0);
    l1 = fmaf(v, Ws[1024 + j], l1);
  }
#pragma unroll 8
  for (int j = 0; j < 512; ++j) {
    float v = hf[(128 + b) * 512 + j];
    l0 = fmaf(v, Ws[512 + j], l0);
    l1 = fmaf(v, Ws[1536 + j], l1);
  }
  float m = fmaxf(l0, l1);
  float lse = m + __logf(__expf(l0 - m) + __expf(l1 - m));
  out[b * 2] = l0 - lse;
  out[b * 2 + 1] = l1 - lse;
}

extern "C" void kernel_launch(void* const* d_in, const int* in_sizes, int n_in,
                              void* d_out, int out_size, void* d_ws, size_t ws_size,
                              hipStream_t stream) {
  const int* X = (const int*)d_in[0];
  const float* emb = (const float*)d_in[1];
  const float* Wih0 = (const float*)d_in[2];
  const float* Whh0 = (const float*)d_in[3];
  const float* bih0 = (const float*)d_in[4];
  const float* bhh0 = (const float*)d_in[5];
  const float* Wih1 = (const float*)d_in[6];
  const float* Whh1 = (const float*)d_in[7];
  const float* bih1 = (const float*)d_in[8];
  const float* bhh1 = (const float*)d_in[9];
  const float* Ws = (const float*)d_in[10];
  const float* bs = (const float*)d_in[11];
  float* out = (float*)d_out;

  const int S = 400, B = 128;
  auto need = [&](int nc) -> size_t {
    size_t TC = (size_t)S / nc, R = TC * B;
    size_t sz = 0;
    sz += R * 3072 * 2;              // giPack
    sz += (size_t)S * B * 1024 * 2;  // y0
    sz += R * 320 * 2;               // embC
    sz += (size_t)3072 * 320 * 2;    // B0p
    sz += (size_t)3072 * 1024 * 2;   // B1p
    sz += 2 * (size_t)1572864 * 2;   // WhhP x2
    sz += 2 * (size_t)4096 * 4;      // biasP x2
    sz += 2 * (size_t)131072 * 4;    // hf x2
    sz += 2 * (size_t)524288 * 2;    // hp x2 (4-slot ring)
    sz += 65536;
    return sz;
  };
  int nc = 16;
  if (need(1) <= ws_size) nc = 1;
  else if (need(2) <= ws_size) nc = 2;
  else if (need(4) <= ws_size) nc = 4;
  else if (need(8) <= ws_size) nc = 8;
  const int TC = S / nc;
  const size_t R = (size_t)TC * B;

  char* p = (char*)d_ws;
  auto alloc = [&](size_t bytes) {
    char* q = p;
    p += (bytes + 255) & ~(size_t)255;
    return q;
  };
  u16* giPack = (u16*)alloc(R * 3072 * 2);
  u16* y0 = (u16*)alloc((size_t)S * B * 1024 * 2);
  u16* embC = (u16*)alloc(R * 320 * 2);
  u16* B0p = (u16*)alloc((size_t)3072 * 320 * 2);
  u16* B1p = (u16*)alloc((size_t)3072 * 1024 * 2);
  u16* WhhP0 = (u16*)alloc((size_t)1572864 * 2);
  u16* WhhP1 = (u16*)alloc((size_t)1572864 * 2);
  float* biasP0 = (float*)alloc(4096 * 4);
  float* biasP1 = (float*)alloc(4096 * 4);
  float* hf0 = (float*)alloc(131072 * 4);
  float* hf1 = (float*)alloc(131072 * 4);
  u16* hp0 = (u16*)alloc(524288 * 2);
  u16* hp1 = (u16*)alloc(524288 * 2);
  u32* flags0 = (u32*)alloc(1024);
  u32* flags1 = (u32*)alloc(1024);

  hipMemsetAsync(hf0, 0, 131072 * 4, stream);
  hipMemsetAsync(hf1, 0, 131072 * 4, stream);
  hipMemsetAsync(hp0, 0, 524288 * 2, stream);
  hipMemsetAsync(hp1, 0, 524288 * 2, stream);
  hipMemsetAsync(flags0, 0, 1024, stream);
  hipMemsetAsync(flags1, 0, 1024, stream);

  pack_wih<<<3840, 256, 0, stream>>>(Wih0, B0p, 300, 320, 3072 * 320);
  pack_wih<<<12288, 256, 0, stream>>>(Wih1, B1p, 1024, 1024, 3072 * 1024);
  pack_whh<<<768, 256, 0, stream>>>(Whh0, WhhP0);
  pack_whh<<<768, 256, 0, stream>>>(Whh1, WhhP1);
  pack_bias<<<16, 256, 0, stream>>>(bih0, bhh0, biasP0);
  pack_bias<<<16, 256, 0, stream>>>(bih1, bhh1, biasP1);

  dim3 gg(24, (unsigned)(R / 128));
  for (int cix = 0; cix < nc; ++cix) {
    int t0 = cix * TC;
    int total = (int)(R * 160);
    gather_emb<<<(total + 255) / 256, 256, 0, stream>>>(X, emb, (u32*)embC, t0, total);
    gemm_f16<<<gg, 256, 0, stream>>>(embC, B0p, giPack, 320);
    gru_layer<<<32, 256, 0, stream>>>(giPack, WhhP0, biasP0, hf0, hp0, y0, flags0, t0, TC);
  }
  for (int cix = 0; cix < nc; ++cix) {
    int t0 = cix * TC;
    gemm_f16<<<gg, 256, 0, stream>>>(y0 + (size_t)t0 * 128 * 1024, B1p, giPack, 1024);
    gru_layer<<<32, 256, 0, stream>>>(giPack, WhhP1, biasP1, hf1, hp1, (u16*)nullptr, flags1, t0, TC);
  }
  classify<<<1, 128, 0, stream>>>(hf1, Ws, bs, out);
}